// Round 5
// baseline (4338.483 us; speedup 1.0000x reference)
//
#include <hip/hip_runtime.h>
#include <stdint.h>

#define Nn 2404
#define Bb 4
#define NP 2560      // padded stride for dual-prop buffers (5 x 512)
#define NK 2432      // padded col count for demand chain (4 x 512 + 384)
#define NKB 1216     // u4 row bytes (NK/2)
#define NR 2432      // padded rows
#define HOPS 76      // DEMAND_HOP + 1
#define DRPB 20      // rows per block in k_dual
#define DCHUNKS 121  // ceil(Nn/DRPB)
#define PBLK 128     // persistent blocks (16 per XCD), 512 threads each
#define RPBK 76      // rows per persistent block (32 blocks per batch x 76 = 2432)

// u4 quantization of At: entries of row-normalized T are in [0, ~8.7e-4].
// Bound 1e-3 -> step 6.67e-5. Round-4 measured end-to-end absmax 0.00390625.
#define Q4INV  15000.0f            // 15 / 1e-3
#define QSTEP4 6.6666667e-5f       // 1e-3 / 15

typedef unsigned int u32x4 __attribute__((ext_vector_type(4)));

__device__ __forceinline__ float bflo(uint32_t u){ return __uint_as_float(u << 16); }
__device__ __forceinline__ float bfhi(uint32_t u){ return __uint_as_float(u & 0xffff0000u); }
__device__ __forceinline__ uint16_t f2bf(float f){
    uint32_t u = __float_as_uint(f);
    u = u + 0x7fffu + ((u >> 16) & 1u);   // RNE
    return (uint16_t)(u >> 16);
}
__device__ __forceinline__ uint32_t q4(float v){
    return (uint32_t)fminf(fmaf(v, Q4INV, 0.5f), 15.0f);   // v >= 0 always
}

// ---- transpose fp32 NxN -> bf16 NR x stride (dst[i][j] = src[j][i], zero-padded) ----
__global__ __launch_bounds__(256) void k_tr(const float* __restrict__ src, uint16_t* __restrict__ dst,
                                            int dstride)
{
    __shared__ float tile[32][33];
    int tx = threadIdx.x, ty = threadIdx.y;
    int j0 = blockIdx.x * 32, i0 = blockIdx.y * 32;
    #pragma unroll
    for (int m = 0; m < 4; ++m){
        int sj = j0 + ty + m * 8;
        int si = i0 + tx;
        tile[ty + m * 8][tx] = (sj < Nn && si < Nn) ? src[(size_t)sj * Nn + si] : 0.f;
    }
    __syncthreads();
    #pragma unroll
    for (int m = 0; m < 4; ++m){
        int di = i0 + ty + m * 8;
        dst[(size_t)di * dstride + j0 + tx] = f2bf(tile[tx][ty + m * 8]);
    }
}

// ---- transpose + quantize fp32 NxN -> u4-packed NR x NKB (dst[i][j] = q4(src[j][i])) ----
__global__ __launch_bounds__(256) void k_trq4(const float* __restrict__ src, uint8_t* __restrict__ dst)
{
    __shared__ float tile[32][33];
    int tx = threadIdx.x, ty = threadIdx.y;
    int j0 = blockIdx.x * 32, i0 = blockIdx.y * 32;
    #pragma unroll
    for (int m = 0; m < 4; ++m){
        int sj = j0 + ty + m * 8;
        int si = i0 + tx;
        tile[ty + m * 8][tx] = (sj < Nn && si < Nn) ? src[(size_t)sj * Nn + si] : 0.f;
    }
    __syncthreads();
    #pragma unroll
    for (int m = 0; m < 4; ++m){
        int di = i0 + ty + m * 8;
        if (tx < 16){
            uint32_t lo = q4(tile[2 * tx][ty + m * 8]);
            uint32_t hi = q4(tile[2 * tx + 1][ty + m * 8]);
            dst[(size_t)di * NKB + (j0 >> 1) + tx] = (uint8_t)(lo | (hi << 4));
        }
    }
}

// ---- copy fp32 NxN -> bf16 NR x NP (zero-padded) ----
__global__ __launch_bounds__(256) void k_cp(const float* __restrict__ src, uint16_t* __restrict__ dst)
{
    int j = blockIdx.x * 256 + threadIdx.x;
    int i = blockIdx.y;
    dst[(size_t)i * NP + j] = (i < Nn && j < Nn) ? f2bf(src[(size_t)i * Nn + j]) : (uint16_t)0;
}

// ---- init col buffers, yall slot 0 (bf16), base, barrier ----
__global__ __launch_bounds__(256) void k_prep(const float* __restrict__ X, const float* __restrict__ ToD,
    const float* __restrict__ DoW, const float* __restrict__ ow, const float* __restrict__ ob,
    float* __restrict__ L1, float* __restrict__ L2, float* __restrict__ L3,
    float* __restrict__ base, uint16_t* __restrict__ yall, unsigned* __restrict__ bar)
{
    int j = blockIdx.x * 256 + threadIdx.x;   // < NP
    int b = blockIdx.y;
    float x = (j < Nn) ? X[b * Nn + j] : 0.f;
    #pragma unroll
    for (int c = 0; c < 3; ++c)  L1[((size_t)(c * Bb + b)) * NP + j] = (c == 0) ? x : 0.f;
    #pragma unroll
    for (int c = 0; c < 7; ++c)  L2[((size_t)(c * Bb + b)) * NP + j] = (c == 0) ? x : 0.f;
    #pragma unroll
    for (int c = 0; c < 15; ++c) L3[((size_t)(c * Bb + b)) * NP + j] = (c == 0) ? x : 0.f;
    if (j < NK) yall[(size_t)b * NK + j] = f2bf(x);    // hop-0 slot
    if (b == 0 && j < 1024) bar[j] = 0u;               // barrier counters
    if (b == 0 && j < NR){
        float v = 0.f;
        if (j < Nn){
            v = ob[j];
            #pragma unroll
            for (int t = 0; t < 24; ++t) v = fmaf(ToD[j * 24 + t], ow[j * 29 + 4 + t], v);
            v = fmaf(DoW[j], ow[j * 29 + 28], v);
        }
        base[j] = v;
    }
}

// ---- dual-prop step: out[(c*Bb+b)][row] = dot(M[row,:], in[(c*Bb+b)][:]) ----
template<int CIN>
__global__ __launch_bounds__(256) void k_dual(const uint16_t* __restrict__ M,
    const float* __restrict__ in, float* __restrict__ out)
{
    int bid = blockIdx.x;
    int b = bid / DCHUNKS, chunk = bid % DCHUNKS;
    int r0 = chunk * DRPB;
    int wave = threadIdx.x >> 6, lane = threadIdx.x & 63;
    for (int rr = 0; rr < DRPB / 4; ++rr){
        int row = r0 + rr * 4 + wave;          // <= 2419 < NR
        const uint16_t* mr = M + (size_t)row * NP;
        float af[40];
        #pragma unroll
        for (int p = 0; p < 5; ++p){
            uint4 av = *(const uint4*)(mr + p * 512 + lane * 8);
            af[p*8+0]=bflo(av.x); af[p*8+1]=bfhi(av.x);
            af[p*8+2]=bflo(av.y); af[p*8+3]=bfhi(av.y);
            af[p*8+4]=bflo(av.z); af[p*8+5]=bfhi(av.z);
            af[p*8+6]=bflo(av.w); af[p*8+7]=bfhi(av.w);
        }
        float acc[CIN];
        #pragma unroll
        for (int c = 0; c < CIN; ++c) acc[c] = 0.f;
        #pragma unroll
        for (int p = 0; p < 5; ++p){
            #pragma unroll
            for (int c = 0; c < CIN; ++c){
                const float* ib = in + ((size_t)(c * Bb + b)) * NP + p * 512 + lane * 8;
                float4 u0 = *(const float4*)(ib);
                float4 u1 = *(const float4*)(ib + 4);
                acc[c] = fmaf(af[p*8+0], u0.x, acc[c]);
                acc[c] = fmaf(af[p*8+1], u0.y, acc[c]);
                acc[c] = fmaf(af[p*8+2], u0.z, acc[c]);
                acc[c] = fmaf(af[p*8+3], u0.w, acc[c]);
                acc[c] = fmaf(af[p*8+4], u1.x, acc[c]);
                acc[c] = fmaf(af[p*8+5], u1.y, acc[c]);
                acc[c] = fmaf(af[p*8+6], u1.z, acc[c]);
                acc[c] = fmaf(af[p*8+7], u1.w, acc[c]);
            }
        }
        #pragma unroll
        for (int c = 0; c < CIN; ++c){
            float v = acc[c];
            #pragma unroll
            for (int off = 32; off; off >>= 1) v += __shfl_down(v, off, 64);
            if (lane == 0) out[((size_t)(c * Bb + b)) * NP + row] = v;
        }
    }
}

// ---- attention logits + softmax over 76 hops; one wave per (b,n) ----
__global__ __launch_bounds__(256) void k_att(const float* __restrict__ S,
    const float* __restrict__ att_w, const float* __restrict__ att_b, float* __restrict__ P)
{
    int wave = threadIdx.x >> 6, lane = threadIdx.x & 63;
    int idx = blockIdx.x * 4 + wave;          // < 9616
    int b = idx / Nn, n = idx % Nn;
    float s[15];
    #pragma unroll
    for (int c = 0; c < 15; ++c) s[c] = S[((size_t)(c * Bb + b)) * NP + n];
    int o1 = lane, o2 = lane + 64;
    const float* aw = att_w + (size_t)n * 15 * HOPS;
    float a1 = att_b[(size_t)n * HOPS + o1];
    #pragma unroll
    for (int c = 0; c < 15; ++c) a1 = fmaf(s[c], aw[c * HOPS + o1], a1);
    float a2 = -1e30f;
    if (o2 < HOPS){
        a2 = att_b[(size_t)n * HOPS + o2];
        #pragma unroll
        for (int c = 0; c < 15; ++c) a2 = fmaf(s[c], aw[c * HOPS + o2], a2);
    }
    float m = fmaxf(a1, a2);
    #pragma unroll
    for (int off = 32; off; off >>= 1) m = fmaxf(m, __shfl_xor(m, off, 64));
    float e1 = __expf(a1 - m);
    float e2 = (o2 < HOPS) ? __expf(a2 - m) : 0.f;
    float t = e1 + e2;
    #pragma unroll
    for (int off = 32; off; off >>= 1) t += __shfl_xor(t, off, 64);
    float inv = 1.f / t;
    P[((size_t)(b * HOPS + o1)) * NR + n] = e1 * inv;
    if (o2 < HOPS) P[((size_t)(b * HOPS + o2)) * NR + n] = e2 * inv;
}

// ---- row-load helper: 5x4B of one u4-packed A-row ----
__device__ __forceinline__ void ldrow4(const uint8_t* __restrict__ ar, int c4b, int lane, uint32_t* av)
{
    #pragma unroll
    for (int p = 0; p < 4; ++p)
        av[p] = *(const uint32_t*)(ar + p * 256 + lane * 4);
    av[4] = *(const uint32_t*)(ar + c4b);
}

// u4 decode + fma; single-accumulator chain (bitwise-identical to round 4)
__device__ __forceinline__ float dotrow4(const uint32_t* av, const float* yv)
{
    float acc = 0.f;
    #pragma unroll
    for (int p = 0; p < 5; ++p){
        uint32_t u = av[p];
        acc = fmaf((float)(u & 15u),          yv[p*8+0], acc);
        acc = fmaf((float)((u >> 4) & 15u),   yv[p*8+1], acc);
        acc = fmaf((float)((u >> 8) & 15u),   yv[p*8+2], acc);
        acc = fmaf((float)((u >> 12) & 15u),  yv[p*8+3], acc);
        acc = fmaf((float)((u >> 16) & 15u),  yv[p*8+4], acc);
        acc = fmaf((float)((u >> 20) & 15u),  yv[p*8+5], acc);
        acc = fmaf((float)((u >> 24) & 15u),  yv[p*8+6], acc);
        acc = fmaf((float)(u >> 28),          yv[p*8+7], acc);
    }
    return acc;
}

// ---- persistent kernel: all 75 hops + hop-0 term + fused Hs (registers) ----
// 128 blocks x 512 threads (co-resident; cooperative launch). Per hop:
//   stage y[k-1] via AGENT-scope (sc1, L2-bypass) loads -> LDS,
//   compute 76 rows/block (u4 At rows stay L2-resident: 1.48 MB/XCD slice),
//   write y[k] via SYSTEM-scope write-through stores (visible in L3),
//   two-level grid barrier: 16 arrivals/XCD-line (8 lines) -> 8 root -> gen.
// No acquire fences anywhere => no buffer_inv => At/P L2 lines survive all hops.
__global__ __launch_bounds__(512) void k_hops(const uint8_t* __restrict__ At,
    uint16_t* __restrict__ yall, const float* __restrict__ P, float* __restrict__ Hs,
    const float* __restrict__ X, unsigned* __restrict__ bar)
{
    __shared__ float ysh[NK];
    const int tid = threadIdx.x;
    const int bid = blockIdx.x;              // 0..127
    const int b   = bid >> 5;                // 32 blocks per batch
    const int r0  = (bid & 31) * RPBK;       // block row base within batch
    const int wave = tid >> 6, lane = tid & 63;
    const int nt = (wave < 4) ? 10 : 9;      // waves 0-3: 10 rows, 4-7: 9 (4*10+4*9=76)

    const bool tail = (lane < 48);           // partial pass: cols 2048..2431
    const int c4  = tail ? (2048 + lane * 8) : (NK - 8);
    const int c4b = tail ? (1024 + lane * 4) : (NKB - 4);

    const float* Pb = P + (size_t)b * HOPS * NR;
    const uint8_t* abase = At + ((size_t)(b * NR + r0 + wave)) * NKB;  // row stride 8*NKB per t

    // hop-0 Hs term (replaces k_hs0), fp32 X as in round 4
    float hs[10];
    #pragma unroll
    for (int t = 0; t < 10; ++t) hs[t] = 0.f;
    if (lane == 0){
        #pragma unroll
        for (int t = 0; t < 10; ++t){
            if (t < nt){
                int row = r0 + wave + 8 * t;
                hs[t] = (row < Nn) ? Pb[row] * X[b * Nn + row] : 0.f;
            }
        }
    }

    unsigned* xcnt = bar + (bid & 7) * 32;   // 8 counter lines, 128B apart
    unsigned* root = bar + 512;
    unsigned* gen  = bar + 544;

    for (int k = 1; k <= 75; ++k){
        // ---- stage y[k-1] -> LDS fp32 (sc1 loads: bypass L2, read L3) ----
        const uint32_t* ys = (const uint32_t*)(yall + ((size_t)(k - 1) * Bb + b) * NK);
        for (int i = tid; i < NK / 2; i += 512){
            uint32_t v = __hip_atomic_load((uint32_t*)(ys + i), __ATOMIC_RELAXED,
                                           __HIP_MEMORY_SCOPE_AGENT);
            ysh[2 * i]     = bflo(v);
            ysh[2 * i + 1] = bfhi(v);
        }
        __syncthreads();

        // ---- y fragment -> registers (identical layout to round 4) ----
        float yv[40];
        #pragma unroll
        for (int p = 0; p < 4; ++p){
            float4 u0 = *(const float4*)(ysh + p * 512 + lane * 8);
            float4 u1 = *(const float4*)(ysh + p * 512 + lane * 8 + 4);
            yv[p*8+0]=u0.x; yv[p*8+1]=u0.y; yv[p*8+2]=u0.z; yv[p*8+3]=u0.w;
            yv[p*8+4]=u1.x; yv[p*8+5]=u1.y; yv[p*8+6]=u1.z; yv[p*8+7]=u1.w;
        }
        {
            float4 u0 = *(const float4*)(ysh + c4);
            float4 u1 = *(const float4*)(ysh + c4 + 4);
            yv[32]=tail?u0.x:0.f; yv[33]=tail?u0.y:0.f; yv[34]=tail?u0.z:0.f; yv[35]=tail?u0.w:0.f;
            yv[36]=tail?u1.x:0.f; yv[37]=tail?u1.y:0.f; yv[38]=tail?u1.z:0.f; yv[39]=tail?u1.w:0.f;
        }

        uint16_t* yn = yall + ((size_t)k * Bb + b) * NK;
        const float* Pk = Pb + (size_t)k * NR;

        // ---- rows: software-prefetched u4 row loads (L2-resident) ----
        uint32_t avc[5], avn[5];
        ldrow4(abase, c4b, lane, avc);
        #pragma unroll
        for (int t = 0; t < 10; ++t){
            if (t < nt){
                if (t + 1 < nt) ldrow4(abase + (size_t)(t + 1) * 8 * NKB, c4b, lane, avn);
                float d = dotrow4(avc, yv);
                #pragma unroll
                for (int off = 32; off; off >>= 1) d += __shfl_down(d, off, 64);
                if (lane == 0){
                    d *= QSTEP4;
                    int row = r0 + wave + 8 * t;
                    __hip_atomic_store(yn + row, f2bf(d), __ATOMIC_RELAXED,
                                       __HIP_MEMORY_SCOPE_SYSTEM);   // write-through
                    hs[t] = fmaf(Pk[row], d, hs[t]);
                }
                #pragma unroll
                for (int p = 0; p < 5; ++p) avc[p] = avn[p];
            }
        }

        // ---- grid barrier: per-wave vmcnt drain, then 2-level arrival tree ----
        __syncthreads();   // drains each wave's y stores (vmcnt 0) before arrival
        if (tid == 0){
            unsigned a = __hip_atomic_fetch_add(xcnt, 1u, __ATOMIC_RELEASE,
                                                __HIP_MEMORY_SCOPE_AGENT);
            if (a == 15u){                     // last of this line's 16 blocks
                __hip_atomic_store(xcnt, 0u, __ATOMIC_RELAXED, __HIP_MEMORY_SCOPE_AGENT);
                unsigned r = __hip_atomic_fetch_add(root, 1u, __ATOMIC_RELEASE,
                                                    __HIP_MEMORY_SCOPE_AGENT);
                if (r == 7u){
                    __hip_atomic_store(root, 0u, __ATOMIC_RELAXED, __HIP_MEMORY_SCOPE_AGENT);
                    __hip_atomic_fetch_add(gen, 1u, __ATOMIC_RELEASE,
                                           __HIP_MEMORY_SCOPE_AGENT);
                }
            }
            while (__hip_atomic_load(gen, __ATOMIC_RELAXED, __HIP_MEMORY_SCOPE_AGENT)
                   < (unsigned)k)
                __builtin_amdgcn_s_sleep(2);
        }
        __syncthreads();
    }

    // ---- write Hs once ----
    if (lane == 0){
        #pragma unroll
        for (int t = 0; t < 10; ++t){
            if (t < nt){
                int row = r0 + wave + 8 * t;
                Hs[b * NR + row] = hs[t];
            }
        }
    }
}

// ---- epilogue: Y[i] = base[i] + sum_b Hs[b][i] * out_w[i][b] ----
__global__ __launch_bounds__(256) void k_final(const float* __restrict__ Hs, const float* __restrict__ base,
    const float* __restrict__ ow, float* __restrict__ Y)
{
    int i = blockIdx.x * 256 + threadIdx.x;
    if (i < Nn){
        float v = base[i];
        #pragma unroll
        for (int b = 0; b < Bb; ++b) v = fmaf(Hs[b * NR + i], ow[i * 29 + b], v);
        Y[i] = v;
    }
}

extern "C" void kernel_launch(void* const* d_in, const int* in_sizes, int n_in,
                              void* d_out, int out_size, void* d_ws, size_t ws_size,
                              hipStream_t stream)
{
    const float* X     = (const float*)d_in[0];
    const float* T     = (const float*)d_in[1];
    const float* Wnorm = (const float*)d_in[4];
    const float* ToD   = (const float*)d_in[5];
    const float* DoW   = (const float*)d_in[6];
    const float* att_w = (const float*)d_in[7];
    const float* att_b = (const float*)d_in[8];
    const float* out_w = (const float*)d_in[9];
    const float* out_b = (const float*)d_in[10];
    float* Y = (float*)d_out;

    char* ws = (char*)d_ws;
    size_t off = 0;
    auto alloc = [&](size_t bytes){ void* p = ws + off; off += (bytes + 255) & ~(size_t)255; return p; };
    uint8_t* At  = (uint8_t*)alloc((size_t)Bb * NR * NKB + 512);       // u4-packed
    uint16_t* Wn  = (uint16_t*)alloc((size_t)NR * NP * 2);
    uint16_t* Wnt = (uint16_t*)alloc((size_t)NR * NP * 2);
    float* L1 = (float*)alloc((size_t)3  * Bb * NP * 4);
    float* L2 = (float*)alloc((size_t)7  * Bb * NP * 4);
    float* L3 = (float*)alloc((size_t)15 * Bb * NP * 4);
    float* P  = (float*)alloc((size_t)Bb * HOPS * NR * 4);
    uint16_t* yall = (uint16_t*)alloc((size_t)HOPS * Bb * NK * 2);     // one bf16 slot per hop
    float* Hs = (float*)alloc((size_t)Bb * NR * 4);
    float* base = (float*)alloc((size_t)NR * 4);
    unsigned* bar = (unsigned*)alloc(4096);
    (void)ws_size; (void)in_sizes; (void)n_in; (void)out_size;

    // stage inputs: At[b] = q4(T[b]^T) (u4-packed), Wn = W_norm, Wnt = W_norm^T (bf16)
    for (int b = 0; b < Bb; ++b)
        k_trq4<<<dim3(NK / 32, NR / 32), dim3(32, 8), 0, stream>>>(T + (size_t)b * Nn * Nn, At + (size_t)b * NR * NKB);
    k_cp<<<dim3(NP / 256, NR), 256, 0, stream>>>(Wnorm, Wn);
    k_tr<<<dim3(NP / 32, NR / 32), dim3(32, 8), 0, stream>>>(Wnorm, Wnt, NP);
    k_prep<<<dim3(NP / 256, Bb), 256, 0, stream>>>(X, ToD, DoW, out_w, out_b, L1, L2, L3, base, yall, bar);

    // dual propagation: L1 = [y, Ay, Ty]; L2 = [y, A@L1, T@L1]; L3 = [y, A@L2, T@L2]
    k_dual<1><<<Bb * DCHUNKS, 256, 0, stream>>>(Wn,  L1, L1 + (size_t)1 * Bb * NP);
    k_dual<1><<<Bb * DCHUNKS, 256, 0, stream>>>(Wnt, L1, L1 + (size_t)2 * Bb * NP);
    k_dual<3><<<Bb * DCHUNKS, 256, 0, stream>>>(Wn,  L1, L2 + (size_t)1 * Bb * NP);
    k_dual<3><<<Bb * DCHUNKS, 256, 0, stream>>>(Wnt, L1, L2 + (size_t)4 * Bb * NP);
    k_dual<7><<<Bb * DCHUNKS, 256, 0, stream>>>(Wn,  L2, L3 + (size_t)1 * Bb * NP);
    k_dual<7><<<Bb * DCHUNKS, 256, 0, stream>>>(Wnt, L2, L3 + (size_t)8 * Bb * NP);

    // attention softmax P[b][hop][n]
    k_att<<<Nn, 256, 0, stream>>>(L3, att_w, att_b, P);

    // all 75 hops in one persistent cooperative kernel (includes hop-0 Hs term)
    {
        void* kargs[6];
        kargs[0] = (void*)&At;
        kargs[1] = (void*)&yall;
        kargs[2] = (void*)&P;
        kargs[3] = (void*)&Hs;
        kargs[4] = (void*)&X;
        kargs[5] = (void*)&bar;
        hipLaunchCooperativeKernel((const void*)k_hops, dim3(PBLK), dim3(512), kargs, 0, stream);
    }

    k_final<<<(Nn + 255) / 256, 256, 0, stream>>>(Hs, base, out_w, Y);
}

// Round 6
// 1195.031 us; speedup vs baseline: 3.6304x; 3.6304x over previous
//
#include <hip/hip_runtime.h>
#include <stdint.h>

#define Nn 2404
#define Bb 4
#define NP 2560      // padded stride for dual-prop buffers (5 x 512)
#define NK 2432      // padded col count for demand chain (4 x 512 + 384)
#define NKB 1216     // u4 row bytes (NK/2)
#define NR 2432      // padded rows
#define HOPS 76      // DEMAND_HOP + 1
#define DRPB 20      // rows per block in k_dual
#define DCHUNKS 121  // ceil(Nn/DRPB)
#define PBLK 128     // persistent blocks (16 per XCD), 512 threads each
#define RPBK 76      // rows per persistent block (32 blocks per batch x 76 = 2432)
#define SMEM_BYTES (RPBK * NKB + NK * 4)   // 92416 At slice + 9728 ysh = 102144

// u4 quantization of At: entries of row-normalized T are in [0, ~8.7e-4].
// Bound 1e-3 -> step 6.67e-5. Measured end-to-end absmax 0.00390625 (r4/r5).
#define Q4INV  15000.0f            // 15 / 1e-3
#define QSTEP4 6.6666667e-5f       // 1e-3 / 15

typedef unsigned int u32x4 __attribute__((ext_vector_type(4)));

__device__ __forceinline__ float bflo(uint32_t u){ return __uint_as_float(u << 16); }
__device__ __forceinline__ float bfhi(uint32_t u){ return __uint_as_float(u & 0xffff0000u); }
__device__ __forceinline__ uint16_t f2bf(float f){
    uint32_t u = __float_as_uint(f);
    u = u + 0x7fffu + ((u >> 16) & 1u);   // RNE
    return (uint16_t)(u >> 16);
}
__device__ __forceinline__ uint32_t q4(float v){
    return (uint32_t)fminf(fmaf(v, Q4INV, 0.5f), 15.0f);   // v >= 0 always
}

// ---- transpose fp32 NxN -> bf16 NR x stride (dst[i][j] = src[j][i], zero-padded) ----
__global__ __launch_bounds__(256) void k_tr(const float* __restrict__ src, uint16_t* __restrict__ dst,
                                            int dstride)
{
    __shared__ float tile[32][33];
    int tx = threadIdx.x, ty = threadIdx.y;
    int j0 = blockIdx.x * 32, i0 = blockIdx.y * 32;
    #pragma unroll
    for (int m = 0; m < 4; ++m){
        int sj = j0 + ty + m * 8;
        int si = i0 + tx;
        tile[ty + m * 8][tx] = (sj < Nn && si < Nn) ? src[(size_t)sj * Nn + si] : 0.f;
    }
    __syncthreads();
    #pragma unroll
    for (int m = 0; m < 4; ++m){
        int di = i0 + ty + m * 8;
        dst[(size_t)di * dstride + j0 + tx] = f2bf(tile[tx][ty + m * 8]);
    }
}

// ---- transpose + quantize fp32 NxN -> u4-packed NR x NKB (dst[i][j] = q4(src[j][i])) ----
__global__ __launch_bounds__(256) void k_trq4(const float* __restrict__ src, uint8_t* __restrict__ dst)
{
    __shared__ float tile[32][33];
    int tx = threadIdx.x, ty = threadIdx.y;
    int j0 = blockIdx.x * 32, i0 = blockIdx.y * 32;
    #pragma unroll
    for (int m = 0; m < 4; ++m){
        int sj = j0 + ty + m * 8;
        int si = i0 + tx;
        tile[ty + m * 8][tx] = (sj < Nn && si < Nn) ? src[(size_t)sj * Nn + si] : 0.f;
    }
    __syncthreads();
    #pragma unroll
    for (int m = 0; m < 4; ++m){
        int di = i0 + ty + m * 8;
        if (tx < 16){
            uint32_t lo = q4(tile[2 * tx][ty + m * 8]);
            uint32_t hi = q4(tile[2 * tx + 1][ty + m * 8]);
            dst[(size_t)di * NKB + (j0 >> 1) + tx] = (uint8_t)(lo | (hi << 4));
        }
    }
}

// ---- copy fp32 NxN -> bf16 NR x NP (zero-padded) ----
__global__ __launch_bounds__(256) void k_cp(const float* __restrict__ src, uint16_t* __restrict__ dst)
{
    int j = blockIdx.x * 256 + threadIdx.x;
    int i = blockIdx.y;
    dst[(size_t)i * NP + j] = (i < Nn && j < Nn) ? f2bf(src[(size_t)i * Nn + j]) : (uint16_t)0;
}

// ---- init col buffers, yall slot 0 (bf16), base, barrier (40KB zeroed) ----
__global__ __launch_bounds__(256) void k_prep(const float* __restrict__ X, const float* __restrict__ ToD,
    const float* __restrict__ DoW, const float* __restrict__ ow, const float* __restrict__ ob,
    float* __restrict__ L1, float* __restrict__ L2, float* __restrict__ L3,
    float* __restrict__ base, uint16_t* __restrict__ yall, unsigned* __restrict__ bar)
{
    int j = blockIdx.x * 256 + threadIdx.x;   // < NP
    int b = blockIdx.y;
    float x = (j < Nn) ? X[b * Nn + j] : 0.f;
    #pragma unroll
    for (int c = 0; c < 3; ++c)  L1[((size_t)(c * Bb + b)) * NP + j] = (c == 0) ? x : 0.f;
    #pragma unroll
    for (int c = 0; c < 7; ++c)  L2[((size_t)(c * Bb + b)) * NP + j] = (c == 0) ? x : 0.f;
    #pragma unroll
    for (int c = 0; c < 15; ++c) L3[((size_t)(c * Bb + b)) * NP + j] = (c == 0) ? x : 0.f;
    if (j < NK) yall[(size_t)b * NK + j] = f2bf(x);    // hop-0 slot
    if (b == 0){                                       // zero barrier region (10240 uints)
        #pragma unroll
        for (int q = 0; q < 4; ++q) bar[j + q * NP] = 0u;
    }
    if (b == 0 && j < NR){
        float v = 0.f;
        if (j < Nn){
            v = ob[j];
            #pragma unroll
            for (int t = 0; t < 24; ++t) v = fmaf(ToD[j * 24 + t], ow[j * 29 + 4 + t], v);
            v = fmaf(DoW[j], ow[j * 29 + 28], v);
        }
        base[j] = v;
    }
}

// ---- dual-prop step: out[(c*Bb+b)][row] = dot(M[row,:], in[(c*Bb+b)][:]) ----
template<int CIN>
__global__ __launch_bounds__(256) void k_dual(const uint16_t* __restrict__ M,
    const float* __restrict__ in, float* __restrict__ out)
{
    int bid = blockIdx.x;
    int b = bid / DCHUNKS, chunk = bid % DCHUNKS;
    int r0 = chunk * DRPB;
    int wave = threadIdx.x >> 6, lane = threadIdx.x & 63;
    for (int rr = 0; rr < DRPB / 4; ++rr){
        int row = r0 + rr * 4 + wave;          // <= 2419 < NR
        const uint16_t* mr = M + (size_t)row * NP;
        float af[40];
        #pragma unroll
        for (int p = 0; p < 5; ++p){
            uint4 av = *(const uint4*)(mr + p * 512 + lane * 8);
            af[p*8+0]=bflo(av.x); af[p*8+1]=bfhi(av.x);
            af[p*8+2]=bflo(av.y); af[p*8+3]=bfhi(av.y);
            af[p*8+4]=bflo(av.z); af[p*8+5]=bfhi(av.z);
            af[p*8+6]=bflo(av.w); af[p*8+7]=bfhi(av.w);
        }
        float acc[CIN];
        #pragma unroll
        for (int c = 0; c < CIN; ++c) acc[c] = 0.f;
        #pragma unroll
        for (int p = 0; p < 5; ++p){
            #pragma unroll
            for (int c = 0; c < CIN; ++c){
                const float* ib = in + ((size_t)(c * Bb + b)) * NP + p * 512 + lane * 8;
                float4 u0 = *(const float4*)(ib);
                float4 u1 = *(const float4*)(ib + 4);
                acc[c] = fmaf(af[p*8+0], u0.x, acc[c]);
                acc[c] = fmaf(af[p*8+1], u0.y, acc[c]);
                acc[c] = fmaf(af[p*8+2], u0.z, acc[c]);
                acc[c] = fmaf(af[p*8+3], u0.w, acc[c]);
                acc[c] = fmaf(af[p*8+4], u1.x, acc[c]);
                acc[c] = fmaf(af[p*8+5], u1.y, acc[c]);
                acc[c] = fmaf(af[p*8+6], u1.z, acc[c]);
                acc[c] = fmaf(af[p*8+7], u1.w, acc[c]);
            }
        }
        #pragma unroll
        for (int c = 0; c < CIN; ++c){
            float v = acc[c];
            #pragma unroll
            for (int off = 32; off; off >>= 1) v += __shfl_down(v, off, 64);
            if (lane == 0) out[((size_t)(c * Bb + b)) * NP + row] = v;
        }
    }
}

// ---- attention logits + softmax over 76 hops; one wave per (b,n) ----
__global__ __launch_bounds__(256) void k_att(const float* __restrict__ S,
    const float* __restrict__ att_w, const float* __restrict__ att_b, float* __restrict__ P)
{
    int wave = threadIdx.x >> 6, lane = threadIdx.x & 63;
    int idx = blockIdx.x * 4 + wave;          // < 9616
    int b = idx / Nn, n = idx % Nn;
    float s[15];
    #pragma unroll
    for (int c = 0; c < 15; ++c) s[c] = S[((size_t)(c * Bb + b)) * NP + n];
    int o1 = lane, o2 = lane + 64;
    const float* aw = att_w + (size_t)n * 15 * HOPS;
    float a1 = att_b[(size_t)n * HOPS + o1];
    #pragma unroll
    for (int c = 0; c < 15; ++c) a1 = fmaf(s[c], aw[c * HOPS + o1], a1);
    float a2 = -1e30f;
    if (o2 < HOPS){
        a2 = att_b[(size_t)n * HOPS + o2];
        #pragma unroll
        for (int c = 0; c < 15; ++c) a2 = fmaf(s[c], aw[c * HOPS + o2], a2);
    }
    float m = fmaxf(a1, a2);
    #pragma unroll
    for (int off = 32; off; off >>= 1) m = fmaxf(m, __shfl_xor(m, off, 64));
    float e1 = __expf(a1 - m);
    float e2 = (o2 < HOPS) ? __expf(a2 - m) : 0.f;
    float t = e1 + e2;
    #pragma unroll
    for (int off = 32; off; off >>= 1) t += __shfl_xor(t, off, 64);
    float inv = 1.f / t;
    P[((size_t)(b * HOPS + o1)) * NR + n] = e1 * inv;
    if (o2 < HOPS) P[((size_t)(b * HOPS + o2)) * NR + n] = e2 * inv;
}

// u4 decode + fma; single-accumulator chain (bitwise-identical to rounds 4/5)
__device__ __forceinline__ float dotrow4(const uint32_t* av, const float* yv)
{
    float acc = 0.f;
    #pragma unroll
    for (int p = 0; p < 5; ++p){
        uint32_t u = av[p];
        acc = fmaf((float)(u & 15u),          yv[p*8+0], acc);
        acc = fmaf((float)((u >> 4) & 15u),   yv[p*8+1], acc);
        acc = fmaf((float)((u >> 8) & 15u),   yv[p*8+2], acc);
        acc = fmaf((float)((u >> 12) & 15u),  yv[p*8+3], acc);
        acc = fmaf((float)((u >> 16) & 15u),  yv[p*8+4], acc);
        acc = fmaf((float)((u >> 20) & 15u),  yv[p*8+5], acc);
        acc = fmaf((float)((u >> 24) & 15u),  yv[p*8+6], acc);
        acc = fmaf((float)(u >> 28),          yv[p*8+7], acc);
    }
    return acc;
}

// ---- persistent kernel: all 75 hops + hop-0 term + fused Hs (registers) ----
// 128 blocks x 512 threads, 1 block/CU (102KB dynamic LDS). The hop-invariant
// At slice (76 rows x 1216B) is staged into LDS ONCE -> zero per-hop At fabric
// traffic. y coherence: sc1 write-through stores / sc1 loads (validated r5,
// bitwise-exact vs multi-dispatch). Barrier: RELAXED-only monotonic 2-level
// tree (no buffer_wbl2, no resets): 8 group lines 4KB apart (16 arrivals each,
// leader = a==16k-1) -> root (finisher = r==8k-1) -> 8 relay lines; pollers
// s_sleep(8) to avoid the r5 poll-storm that saturated the coherence point.
__global__ __launch_bounds__(512) void k_hops(const uint8_t* __restrict__ At,
    uint16_t* __restrict__ yall, const float* __restrict__ P, float* __restrict__ Hs,
    const float* __restrict__ X, unsigned* __restrict__ bar)
{
    extern __shared__ uint8_t smem[];
    uint8_t* ash = smem;                          // [RPBK][NKB] u4 rows
    float*   ysh = (float*)(smem + RPBK * NKB);   // [NK] fp32
    const int tid = threadIdx.x;
    const int bid = blockIdx.x;              // 0..127
    const int b   = bid >> 5;                // 32 blocks per batch
    const int r0  = (bid & 31) * RPBK;       // block row base within batch
    const int wave = tid >> 6, lane = tid & 63;
    const int nt = (wave < 4) ? 10 : 9;      // waves 0-3: 10 rows, 4-7: 9 (4*10+4*9=76)

    const bool tail = (lane < 48);           // partial pass: cols 2048..2431
    const int c4  = tail ? (2048 + lane * 8) : (NK - 8);
    const int c4b = tail ? (1024 + lane * 4) : (NKB - 4);

    // ---- stage this block's hop-invariant At slice into LDS (once) ----
    {
        const u32x4* src = (const u32x4*)(At + ((size_t)(b * NR + r0)) * NKB);
        u32x4* dst = (u32x4*)ash;
        for (int i = tid; i < (RPBK * NKB) / 16; i += 512) dst[i] = src[i];
    }

    const float* Pb = P + (size_t)b * HOPS * NR;

    // hop-0 Hs term (replaces k_hs0)
    float hs[10];
    #pragma unroll
    for (int t = 0; t < 10; ++t) hs[t] = 0.f;
    if (lane == 0){
        #pragma unroll
        for (int t = 0; t < 10; ++t){
            if (t < nt){
                int row = r0 + wave + 8 * t;
                hs[t] = (row < Nn) ? Pb[row] * X[b * Nn + row] : 0.f;
            }
        }
    }

    unsigned* grp  = bar + (size_t)(bid & 7) * 1024;   // 4KB-spaced group counters
    unsigned* root = bar + 8192;
    unsigned* rly  = bar + 8256 + (bid & 7) * 16;      // 64B-spaced relay lines

    for (int k = 1; k <= 75; ++k){
        // ---- stage y[k-1] -> LDS fp32 (sc1 loads: bypass L2, read L3) ----
        const uint32_t* ys = (const uint32_t*)(yall + ((size_t)(k - 1) * Bb + b) * NK);
        for (int i = tid; i < NK / 2; i += 512){
            uint32_t v = __hip_atomic_load((uint32_t*)(ys + i), __ATOMIC_RELAXED,
                                           __HIP_MEMORY_SCOPE_AGENT);
            ysh[2 * i]     = bflo(v);
            ysh[2 * i + 1] = bfhi(v);
        }
        __syncthreads();   // (also covers the one-time At staging on k==1)

        // ---- y fragment -> registers (identical layout to round 4/5) ----
        float yv[40];
        #pragma unroll
        for (int p = 0; p < 4; ++p){
            float4 u0 = *(const float4*)(ysh + p * 512 + lane * 8);
            float4 u1 = *(const float4*)(ysh + p * 512 + lane * 8 + 4);
            yv[p*8+0]=u0.x; yv[p*8+1]=u0.y; yv[p*8+2]=u0.z; yv[p*8+3]=u0.w;
            yv[p*8+4]=u1.x; yv[p*8+5]=u1.y; yv[p*8+6]=u1.z; yv[p*8+7]=u1.w;
        }
        {
            float4 u0 = *(const float4*)(ysh + c4);
            float4 u1 = *(const float4*)(ysh + c4 + 4);
            yv[32]=tail?u0.x:0.f; yv[33]=tail?u0.y:0.f; yv[34]=tail?u0.z:0.f; yv[35]=tail?u0.w:0.f;
            yv[36]=tail?u1.x:0.f; yv[37]=tail?u1.y:0.f; yv[38]=tail?u1.z:0.f; yv[39]=tail?u1.w:0.f;
        }

        uint16_t* yn = yall + ((size_t)k * Bb + b) * NK;
        const float* Pk = Pb + (size_t)k * NR;

        // ---- rows from LDS (bank-conflict-free: lane-consecutive 4B) ----
        #pragma unroll
        for (int t = 0; t < 10; ++t){
            if (t < nt){
                const uint8_t* ar = ash + (unsigned)(wave + 8 * t) * NKB;
                uint32_t av[5];
                #pragma unroll
                for (int p = 0; p < 4; ++p)
                    av[p] = *(const uint32_t*)(ar + p * 256 + lane * 4);
                av[4] = *(const uint32_t*)(ar + c4b);
                float d = dotrow4(av, yv);
                #pragma unroll
                for (int off = 32; off; off >>= 1) d += __shfl_down(d, off, 64);
                if (lane == 0){
                    d *= QSTEP4;
                    int row = r0 + wave + 8 * t;
                    __hip_atomic_store(yn + row, f2bf(d), __ATOMIC_RELAXED,
                                       __HIP_MEMORY_SCOPE_SYSTEM);   // write-through
                    hs[t] = fmaf(Pk[row], d, hs[t]);
                }
            }
        }

        // ---- grid barrier: vmcnt drain, then relaxed monotonic 2-level tree ----
        __syncthreads();   // drains each wave's y stores before arrival
        if (tid == 0){
            unsigned a = __hip_atomic_fetch_add(grp, 1u, __ATOMIC_RELAXED,
                                                __HIP_MEMORY_SCOPE_AGENT);
            if (a == (unsigned)(16 * k - 1)){          // last of this group's 16
                unsigned r = __hip_atomic_fetch_add(root, 1u, __ATOMIC_RELAXED,
                                                    __HIP_MEMORY_SCOPE_AGENT);
                if (r == (unsigned)(8 * k - 1)){       // global last
                    #pragma unroll
                    for (int g = 0; g < 8; ++g)
                        __hip_atomic_store(bar + 8256 + g * 16, (unsigned)k,
                                           __ATOMIC_RELAXED, __HIP_MEMORY_SCOPE_AGENT);
                }
            }
            while (__hip_atomic_load(rly, __ATOMIC_RELAXED, __HIP_MEMORY_SCOPE_AGENT)
                   < (unsigned)k)
                __builtin_amdgcn_s_sleep(8);
        }
        __syncthreads();
    }

    // ---- write Hs once ----
    if (lane == 0){
        #pragma unroll
        for (int t = 0; t < 10; ++t){
            if (t < nt){
                int row = r0 + wave + 8 * t;
                Hs[b * NR + row] = hs[t];
            }
        }
    }
}

// ---- epilogue: Y[i] = base[i] + sum_b Hs[b][i] * out_w[i][b] ----
__global__ __launch_bounds__(256) void k_final(const float* __restrict__ Hs, const float* __restrict__ base,
    const float* __restrict__ ow, float* __restrict__ Y)
{
    int i = blockIdx.x * 256 + threadIdx.x;
    if (i < Nn){
        float v = base[i];
        #pragma unroll
        for (int b = 0; b < Bb; ++b) v = fmaf(Hs[b * NR + i], ow[i * 29 + b], v);
        Y[i] = v;
    }
}

extern "C" void kernel_launch(void* const* d_in, const int* in_sizes, int n_in,
                              void* d_out, int out_size, void* d_ws, size_t ws_size,
                              hipStream_t stream)
{
    const float* X     = (const float*)d_in[0];
    const float* T     = (const float*)d_in[1];
    const float* Wnorm = (const float*)d_in[4];
    const float* ToD   = (const float*)d_in[5];
    const float* DoW   = (const float*)d_in[6];
    const float* att_w = (const float*)d_in[7];
    const float* att_b = (const float*)d_in[8];
    const float* out_w = (const float*)d_in[9];
    const float* out_b = (const float*)d_in[10];
    float* Y = (float*)d_out;

    char* ws = (char*)d_ws;
    size_t off = 0;
    auto alloc = [&](size_t bytes){ void* p = ws + off; off += (bytes + 255) & ~(size_t)255; return p; };
    uint8_t* At  = (uint8_t*)alloc((size_t)Bb * NR * NKB + 512);       // u4-packed
    uint16_t* Wn  = (uint16_t*)alloc((size_t)NR * NP * 2);
    uint16_t* Wnt = (uint16_t*)alloc((size_t)NR * NP * 2);
    float* L1 = (float*)alloc((size_t)3  * Bb * NP * 4);
    float* L2 = (float*)alloc((size_t)7  * Bb * NP * 4);
    float* L3 = (float*)alloc((size_t)15 * Bb * NP * 4);
    float* P  = (float*)alloc((size_t)Bb * HOPS * NR * 4);
    uint16_t* yall = (uint16_t*)alloc((size_t)HOPS * Bb * NK * 2);     // one bf16 slot per hop
    float* Hs = (float*)alloc((size_t)Bb * NR * 4);
    float* base = (float*)alloc((size_t)NR * 4);
    unsigned* bar = (unsigned*)alloc(40960);                           // 10240 uints
    (void)ws_size; (void)in_sizes; (void)n_in; (void)out_size;

    // allow >64KB dynamic LDS for k_hops (idempotent host-side call)
    hipFuncSetAttribute((const void*)k_hops, hipFuncAttributeMaxDynamicSharedMemorySize,
                        SMEM_BYTES);

    // stage inputs: At[b] = q4(T[b]^T) (u4-packed), Wn = W_norm, Wnt = W_norm^T (bf16)
    for (int b = 0; b < Bb; ++b)
        k_trq4<<<dim3(NK / 32, NR / 32), dim3(32, 8), 0, stream>>>(T + (size_t)b * Nn * Nn, At + (size_t)b * NR * NKB);
    k_cp<<<dim3(NP / 256, NR), 256, 0, stream>>>(Wnorm, Wn);
    k_tr<<<dim3(NP / 32, NR / 32), dim3(32, 8), 0, stream>>>(Wnorm, Wnt, NP);
    k_prep<<<dim3(NP / 256, Bb), 256, 0, stream>>>(X, ToD, DoW, out_w, out_b, L1, L2, L3, base, yall, bar);

    // dual propagation: L1 = [y, Ay, Ty]; L2 = [y, A@L1, T@L1]; L3 = [y, A@L2, T@L2]
    k_dual<1><<<Bb * DCHUNKS, 256, 0, stream>>>(Wn,  L1, L1 + (size_t)1 * Bb * NP);
    k_dual<1><<<Bb * DCHUNKS, 256, 0, stream>>>(Wnt, L1, L1 + (size_t)2 * Bb * NP);
    k_dual<3><<<Bb * DCHUNKS, 256, 0, stream>>>(Wn,  L1, L2 + (size_t)1 * Bb * NP);
    k_dual<3><<<Bb * DCHUNKS, 256, 0, stream>>>(Wnt, L1, L2 + (size_t)4 * Bb * NP);
    k_dual<7><<<Bb * DCHUNKS, 256, 0, stream>>>(Wn,  L2, L3 + (size_t)1 * Bb * NP);
    k_dual<7><<<Bb * DCHUNKS, 256, 0, stream>>>(Wnt, L2, L3 + (size_t)8 * Bb * NP);

    // attention softmax P[b][hop][n]
    k_att<<<Nn, 256, 0, stream>>>(L3, att_w, att_b, P);

    // all 75 hops in one persistent cooperative kernel (includes hop-0 Hs term)
    {
        void* kargs[6];
        kargs[0] = (void*)&At;
        kargs[1] = (void*)&yall;
        kargs[2] = (void*)&P;
        kargs[3] = (void*)&Hs;
        kargs[4] = (void*)&X;
        kargs[5] = (void*)&bar;
        hipLaunchCooperativeKernel((const void*)k_hops, dim3(PBLK), dim3(512), kargs,
                                   SMEM_BYTES, stream);
    }

    k_final<<<(Nn + 255) / 256, 256, 0, stream>>>(Hs, base, out_w, Y);
}